// Round 7
// baseline (256.873 us; speedup 1.0000x reference)
//
#include <hip/hip_runtime.h>
#include <math.h>

typedef unsigned short u16;
using bf16x8   = __attribute__((ext_vector_type(8))) __bf16;
using floatx4  = __attribute__((ext_vector_type(4))) float;
using ushortx8 = __attribute__((ext_vector_type(8))) unsigned short;
using ushortx4 = __attribute__((ext_vector_type(4))) unsigned short;
using uintx4   = __attribute__((ext_vector_type(4))) unsigned int;
using uintx2   = __attribute__((ext_vector_type(2))) unsigned int;

// round-half-up fp32->bf16
static __device__ __forceinline__ u16 f2bf(float f) {
  return (u16)((__float_as_uint(f) + 0x8000u) >> 16);
}
// pack two fp32 -> two bf16 in one u32
static __device__ __forceinline__ unsigned int pk2bf(float lo, float hi) {
#if __has_builtin(__builtin_amdgcn_cvt_pk_bf16_f32)
  typedef __attribute__((ext_vector_type(2))) __bf16 bf16x2_t;
  bf16x2_t r = __builtin_amdgcn_cvt_pk_bf16_f32(lo, hi);
  return *(unsigned int*)&r;
#else
  return __builtin_amdgcn_perm(__float_as_uint(hi) + 0x8000u,
                               __float_as_uint(lo) + 0x8000u, 0x07060302u);
#endif
}
// raw v_exp_f32 (2^x) — inputs bounded, skip denormal legalization
static __device__ __forceinline__ float fast_exp2(float x) {
#if __has_builtin(__builtin_amdgcn_exp2f)
  return __builtin_amdgcn_exp2f(x);
#else
  return exp2f(x);
#endif
}
static __device__ __forceinline__ float fast_rcp(float x) {
#if __has_builtin(__builtin_amdgcn_rcpf)
  return __builtin_amdgcn_rcpf(x);
#else
  return 1.0f / x;
#endif
}
// async global->LDS, 16B per lane; LDS dest = base + lane*16
static __device__ __forceinline__ void gload_lds16(const void* g, void* l) {
  __builtin_amdgcn_global_load_lds(
      (const __attribute__((address_space(1))) unsigned int*)g,
      (__attribute__((address_space(3))) unsigned int*)l, 16, 0, 0);
}

// ---------------------------------------------------------------------------
// Fused prep: x fp32->bf16  +  W_qkv transpose  +  W_out transpose.
// ---------------------------------------------------------------------------
static __device__ __forceinline__ void transW_tile(
    const float* __restrict__ W, u16* __restrict__ WT, int K, int N,
    int bx, int by, float (*tile)[68], int t) {
  const int kb = by * 64, nb = bx * 64;
  {
    const int kl = t >> 2, nc = (t & 3) * 16;
    const float* src = W + (size_t)(kb + kl) * N + nb + nc;
    #pragma unroll
    for (int c = 0; c < 4; c++)
      *(floatx4*)&tile[kl][nc + c * 4] = *(const floatx4*)(src + c * 4);
  }
  __syncthreads();
  {
    const int nl = t >> 2, kc = (t & 3) * 16;
    uintx4 u0, u1;
    #pragma unroll
    for (int j = 0; j < 4; j++)
      u0[j] = pk2bf(tile[kc + 2 * j][nl], tile[kc + 2 * j + 1][nl]);
    #pragma unroll
    for (int j = 0; j < 4; j++)
      u1[j] = pk2bf(tile[kc + 8 + 2 * j][nl], tile[kc + 9 + 2 * j][nl]);
    u16* dst = WT + (size_t)(nb + nl) * K + kb + kc;
    *(uintx4*)dst = u0;
    *(uintx4*)(dst + 8) = u1;
  }
}

__global__ __launch_bounds__(256) void prep(
    const float* __restrict__ x, const float* __restrict__ Wqkv,
    const float* __restrict__ Wout, u16* __restrict__ Xb,
    u16* __restrict__ WqT, u16* __restrict__ WoT) {
  __shared__ float tile[64][68];
  const int blk = blockIdx.x;
  const int t = threadIdx.x;
  if (blk < 4096) {
    const int i = (blk * 256 + t) * 8;
    floatx4 f0 = *(const floatx4*)(x + i);
    floatx4 f1 = *(const floatx4*)(x + i + 4);
    uintx4 u;
    u[0] = pk2bf(f0[0], f0[1]); u[1] = pk2bf(f0[2], f0[3]);
    u[2] = pk2bf(f1[0], f1[1]); u[3] = pk2bf(f1[2], f1[3]);
    *(uintx4*)(Xb + i) = u;
  } else if (blk < 4096 + 768) {
    const int b2 = blk - 4096;                 // 48 x 16
    transW_tile(Wqkv, WqT, 1024, 3072, b2 % 48, b2 / 48, tile, t);
  } else {
    const int b3 = blk - 4096 - 768;           // 16 x 16
    transW_tile(Wout, WoT, 1024, 1024, b3 % 16, b3 / 16, tile, t);
  }
}

// ---------------------------------------------------------------------------
// GEMM  C[M,N] = A[M,K](bf16) @ B^T[N,K](bf16)^T + bias.  128x128, BK=64.
// Both operands staged via global_load_lds, XOR-swizzled 8-elem k-chunks.
// OUT==0 (round-5 proven): unswapped loop; scatter Q(scaled)/K [B,H,T,D]
//        scalar + V^T [B,H,D,T] packed.
// OUT==1: operand-swapped loop (acc reg dim = n) -> packed floatx4 + bias.
// Template => each instantiation is single-path.
// ---------------------------------------------------------------------------
template <int OUT>
__global__ __launch_bounds__(256) void gemm128(
    const u16* __restrict__ A, const u16* __restrict__ Bt,
    const float* __restrict__ bias,
    u16* __restrict__ Qb, u16* __restrict__ Kb, u16* __restrict__ Vt,
    float* __restrict__ Out, int N, int K)
{
  __shared__ u16 As[128 * 64];
  __shared__ u16 Bs[128 * 64];

  const int tid  = threadIdx.x;
  const int wave = tid >> 6, lane = tid & 63;
  const int quad = lane >> 4, l15 = lane & 15;
  const int lrow = lane >> 3;                 // 0..7
  const int scol = ((lane & 7) ^ lrow) * 8;   // swizzled k-offset (elements)

  const int rowBase = blockIdx.y * 128;
  const int colBase = blockIdx.x * 128;
  const int wRow = (wave >> 1) * 64;
  const int wCol = (wave & 1) * 64;

  floatx4 acc[4][4];
  #pragma unroll
  for (int i = 0; i < 4; i++)
    #pragma unroll
    for (int j = 0; j < 4; j++)
      acc[i][j] = floatx4{0.f, 0.f, 0.f, 0.f};

  const u16* Ap = A  + (size_t)(rowBase + (wave * 4) * 8 + lrow) * K + scol;
  const u16* Bp = Bt + (size_t)(colBase + (wave * 4) * 8 + lrow) * K + scol;

  for (int k0 = 0; k0 < K; k0 += 64) {
    __syncthreads();
    #pragma unroll
    for (int i = 0; i < 4; i++) {
      const int c = wave * 4 + i;
      gload_lds16(Ap + (size_t)(i * 8) * K + k0, &As[c * 512]);
      gload_lds16(Bp + (size_t)(i * 8) * K + k0, &Bs[c * 512]);
    }
    __syncthreads();

    #pragma unroll
    for (int ks = 0; ks < 2; ks++) {
      const int sw = (((ks << 2) | quad) ^ (l15 & 7)) << 3;
      bf16x8 a[4], b[4];
      #pragma unroll
      for (int mt = 0; mt < 4; mt++)
        a[mt] = *(const bf16x8*)&As[(wRow + mt * 16 + l15) * 64 + sw];
      #pragma unroll
      for (int nt = 0; nt < 4; nt++)
        b[nt] = *(const bf16x8*)&Bs[(wCol + nt * 16 + l15) * 64 + sw];
      if constexpr (OUT == 0) {
        #pragma unroll
        for (int mt = 0; mt < 4; mt++)
          #pragma unroll
          for (int nt = 0; nt < 4; nt++)
            acc[mt][nt] = __builtin_amdgcn_mfma_f32_16x16x32_bf16(a[mt], b[nt], acc[mt][nt], 0, 0, 0);
      } else {
        #pragma unroll
        for (int nt = 0; nt < 4; nt++)
          #pragma unroll
          for (int mt = 0; mt < 4; mt++)
            acc[nt][mt] = __builtin_amdgcn_mfma_f32_16x16x32_bf16(b[nt], a[mt], acc[nt][mt], 0, 0, 0);
      }
    }
  }

  if constexpr (OUT == 0) {
    const int which = colBase >> 10;            // block-uniform: 0=Q 1=K 2=V
    const int cb = colBase & 1023;
    const float qscale = 0.18033688011112042f;  // 0.125 * log2(e) -> softmax uses exp2
    #pragma unroll
    for (int mt = 0; mt < 4; mt++) {
      const int gm0 = rowBase + wRow + mt * 16 + quad * 4;
      const int bb = gm0 >> 11, t0 = gm0 & 2047;
      #pragma unroll
      for (int nt = 0; nt < 4; nt++) {
        const int gn = colBase + wCol + nt * 16 + l15;
        const int gl = cb + wCol + nt * 16 + l15;
        const float bv = bias[gn];
        const int h = gl >> 6, d = gl & 63;
        const int bh = bb * 16 + h;
        if (which == 2) {
          ushortx4 pk;
          #pragma unroll
          for (int r = 0; r < 4; r++) pk[r] = f2bf(acc[mt][nt][r] + bv);
          *(ushortx4*)&Vt[((size_t)bh * 64 + d) * 2048 + t0] = pk;   // V^T [B,H,D,T]
        } else if (which == 0) {
          #pragma unroll
          for (int r = 0; r < 4; r++)
            Qb[((size_t)bh * 2048 + t0 + r) * 64 + d] = f2bf((acc[mt][nt][r] + bv) * qscale);
        } else {
          #pragma unroll
          for (int r = 0; r < 4; r++)
            Kb[((size_t)bh * 2048 + t0 + r) * 64 + d] = f2bf(acc[mt][nt][r] + bv);
        }
      }
    }
  } else {
    // swapped epilogue: packed dwordx4 fp32 stores
    #pragma unroll
    for (int nt = 0; nt < 4; nt++) {
      const int gn0 = colBase + wCol + nt * 16 + quad * 4;
      const floatx4 bv = *(const floatx4*)&bias[gn0];
      #pragma unroll
      for (int mt = 0; mt < 4; mt++) {
        const int gm = rowBase + wRow + mt * 16 + l15;
        floatx4 v = acc[nt][mt] + bv;
        *(floatx4*)&Out[(size_t)gm * N + gn0] = v;
      }
    }
  }
}

// ---------------------------------------------------------------------------
// Flash attention, causal, softmax-lite, transposed score path, ping-pong K/V.
// Per-(wave,mt) private swizzled Pt buffers (8 x 1024 elems = all of Qs):
// S^T both mt -> exp/pack/write both -> PV both; mt1's exp work hides mt0's
// Pt LDS write->read latency.
// One block = (b,h) x 128 q-rows; 4 waves x 32 rows; 64-key tiles.
// LDS: Qs 16K (reused as Pt) + Ks[2] 16K + Vs[2] 16K = 48 KB.
// ---------------------------------------------------------------------------
__global__ __launch_bounds__(256) void attn_fa(
    const u16* __restrict__ Qb, const u16* __restrict__ Kb,
    const u16* __restrict__ Vt, u16* __restrict__ Ob)
{
  __shared__ u16 Qs[128 * 64];
  __shared__ u16 Ks[2][64 * 64], Vs[2][64 * 64];

  const int tid  = threadIdx.x;
  const int wave = tid >> 6, lane = tid & 63;
  const int quad = lane >> 4, l15 = lane & 15;
  const int lrow = lane >> 3;
  const int scol = ((lane & 7) ^ lrow) * 8;

  const int bh    = blockIdx.x;            // b*16 + h
  const int qt    = 15 - (int)blockIdx.y;  // descending: long blocks first
  const int qbase = qt * 128;

  const u16* Qp = Qb + (size_t)bh * 2048 * 64;
  const u16* Kp = Kb + (size_t)bh * 2048 * 64;
  const u16* Vp = Vt + (size_t)bh * 64 * 2048;

  // prologue: Q tile + K/V tile 0
  #pragma unroll
  for (int i = 0; i < 4; i++) {
    const int c = wave * 4 + i;
    gload_lds16(Qp + (size_t)(qbase + c * 8 + lrow) * 64 + scol, &Qs[c * 512]);
  }
  #pragma unroll
  for (int i = 0; i < 2; i++) {
    const int c = wave * 2 + i;
    gload_lds16(Kp + (size_t)(c * 8 + lrow) * 64 + scol, &Ks[0][c * 512]);
    gload_lds16(Vp + (size_t)(c * 8 + lrow) * 2048 + scol, &Vs[0][c * 512]);
  }
  __syncthreads();

  const int swA0 = (quad ^ (l15 & 7)) * 8;
  const int swA1 = ((4 + quad) ^ (l15 & 7)) * 8;
  bf16x8 aq[2][2];
  #pragma unroll
  for (int mt = 0; mt < 2; mt++) {
    const int row = wave * 32 + mt * 16 + l15;
    aq[mt][0] = *(const bf16x8*)&Qs[row * 64 + swA0];
    aq[mt][1] = *(const bf16x8*)&Qs[row * 64 + swA1];
  }
  __syncthreads();   // all aq reads done before any Pt write (Qs overlay)

  // per-(wave,mt) swizzled Pt tiles [q=16][key=64], stride 64, XOR-swizzled
  u16* Pt0 = &Qs[(wave * 2 + 0) * 1024];
  u16* Pt1 = &Qs[(wave * 2 + 1) * 1024];
  // write offset within a row: off = ct*16 + quad*4 -> swizzled 8-chunk
  const int pwr = l15 * 64 + (quad & 1) * 4;   // row base + intra-chunk half
  const int pw_x = (quad >> 1);                // chunk parity from quad

  floatx4 o[2][4];
  #pragma unroll
  for (int mt = 0; mt < 2; mt++)
    #pragma unroll
    for (int dt = 0; dt < 4; dt++) o[mt][dt] = floatx4{0.f, 0.f, 0.f, 0.f};
  float lsum[2] = {0.f, 0.f};

  const int rowmax = qbase + wave * 32 + 31;
  const int nk = 2 * qt + 2;
  for (int kt = 0; kt < nk; kt++) {
    const int kbase = kt * 64;
    const int cur = kt & 1;
    // issue next tile's staging before computing this one
    if (kt + 1 < nk) {
      const int nb = kbase + 64;
      #pragma unroll
      for (int i = 0; i < 2; i++) {
        const int c = wave * 2 + i;
        gload_lds16(Kp + (size_t)(nb + c * 8 + lrow) * 64 + scol, &Ks[cur ^ 1][c * 512]);
        gload_lds16(Vp + (size_t)(c * 8 + lrow) * 2048 + nb + scol, &Vs[cur ^ 1][c * 512]);
      }
    }

    if (kbase <= rowmax) {
      // K fragments (shared by both mt)
      bf16x8 kf[4][2];
      #pragma unroll
      for (int ct = 0; ct < 4; ct++) {
        const int row = ct * 16 + l15;
        kf[ct][0] = *(const bf16x8*)&Ks[cur][row * 64 + swA0];
        kf[ct][1] = *(const bf16x8*)&Ks[cur][row * 64 + swA1];
      }

      // S^T for BOTH mt subtiles
      floatx4 st[2][4];
      #pragma unroll
      for (int mt = 0; mt < 2; mt++)
        #pragma unroll
        for (int ct = 0; ct < 4; ct++) {
          floatx4 z = floatx4{0.f, 0.f, 0.f, 0.f};
          z          = __builtin_amdgcn_mfma_f32_16x16x32_bf16(kf[ct][0], aq[mt][0], z, 0, 0, 0);
          st[mt][ct] = __builtin_amdgcn_mfma_f32_16x16x32_bf16(kf[ct][1], aq[mt][1], z, 0, 0, 0);
        }

      // V fragments (issue early; independent of exp)
      bf16x8 vf[4][2];
      #pragma unroll
      for (int ct = 0; ct < 4; ct++) {
        const int row = ct * 16 + l15;
        vf[ct][0] = *(const bf16x8*)&Vs[cur][row * 64 + swA0];
        vf[ct][1] = *(const bf16x8*)&Vs[cur][row * 64 + swA1];
      }

      // exp / mask / pack / write for both mt (fills Pt LDS latency)
      #pragma unroll
      for (int mt = 0; mt < 2; mt++) {
        const int rowmin = qbase + wave * 32 + mt * 16;
        const bool needmask = (kbase + 63 > rowmin);
        const int qg = rowmin + l15;
        u16* Ptm = mt ? Pt1 : Pt0;
        float ls = 0.f;
        #pragma unroll
        for (int ct = 0; ct < 4; ct++) {
          float p0 = fast_exp2(st[mt][ct][0]), p1 = fast_exp2(st[mt][ct][1]);
          float p2 = fast_exp2(st[mt][ct][2]), p3 = fast_exp2(st[mt][ct][3]);
          if (needmask) {
            const int k0i = kbase + ct * 16 + quad * 4;
            if (k0i + 0 > qg) p0 = 0.f;
            if (k0i + 1 > qg) p1 = 0.f;
            if (k0i + 2 > qg) p2 = 0.f;
            if (k0i + 3 > qg) p3 = 0.f;
          }
          ls += (p0 + p1) + (p2 + p3);
          uintx2 w;
          w[0] = pk2bf(p0, p1);
          w[1] = pk2bf(p2, p3);
          const int chunk = ct * 2 + pw_x;
          *(uintx2*)&Ptm[pwr + ((chunk ^ (l15 & 7)) << 3)] = w;   // ds_write_b64
        }
        lsum[mt] += ls;
      }

      // PV for both mt
      #pragma unroll
      for (int mt = 0; mt < 2; mt++) {
        u16* Ptm = mt ? Pt1 : Pt0;
        const bf16x8 pb0 = *(const bf16x8*)&Ptm[l15 * 64 + swA0];
        const bf16x8 pb1 = *(const bf16x8*)&Ptm[l15 * 64 + swA1];
        #pragma unroll
        for (int dt = 0; dt < 4; dt++) {
          o[mt][dt] = __builtin_amdgcn_mfma_f32_16x16x32_bf16(vf[dt][0], pb0, o[mt][dt], 0, 0, 0);
          o[mt][dt] = __builtin_amdgcn_mfma_f32_16x16x32_bf16(vf[dt][1], pb1, o[mt][dt], 0, 0, 0);
        }
      }
    }
    __syncthreads();   // frees buf[cur] for kt+2, drains kt+1 loads
  }

  // epilogue: reduce row-sums across quads, normalize, packed 8B stores
  const int bb = bh >> 4, h = bh & 15;
  #pragma unroll
  for (int mt = 0; mt < 2; mt++) {
    float l = lsum[mt];
    l += __shfl_xor(l, 16);
    l += __shfl_xor(l, 32);
    const float linv = fast_rcp(l);
    const int t = qbase + wave * 32 + mt * 16 + l15;
    u16* dst = Ob + ((size_t)(bb * 2048 + t)) * 1024 + h * 64 + quad * 4;
    #pragma unroll
    for (int dt = 0; dt < 4; dt++) {
      uintx2 w;
      w[0] = pk2bf(o[mt][dt][0] * linv, o[mt][dt][1] * linv);
      w[1] = pk2bf(o[mt][dt][2] * linv, o[mt][dt][3] * linv);
      *(uintx2*)(dst + dt * 16) = w;
    }
  }
}

// ---------------------------------------------------------------------------
extern "C" void kernel_launch(void* const* d_in, const int* in_sizes, int n_in,
                              void* d_out, int out_size, void* d_ws, size_t ws_size,
                              hipStream_t stream) {
  const float* x    = (const float*)d_in[0];
  const float* Wqkv = (const float*)d_in[1];
  const float* bqkv = (const float*)d_in[2];
  const float* Wout = (const float*)d_in[3];
  const float* bout = (const float*)d_in[4];

  // workspace (u16 elems), 75.5 MB total:
  //  Xb (x bf16, reused as Ob) | WqT | WoT | Qb | Kb | Vt
  const size_t NB = (size_t)8192 * 1024;
  u16* Xb  = (u16*)d_ws;               // also Ob
  u16* WqT = Xb + NB;
  u16* WoT = WqT + (size_t)3072 * 1024;
  u16* Qb  = WoT + (size_t)1024 * 1024;
  u16* Kb  = Qb + NB;
  u16* Vt  = Kb + NB;

  // 1) fused prep: x->bf16, Wqkv^T, Wout^T
  prep<<<5120, 256, 0, stream>>>(x, Wqkv, Wout, Xb, WqT, WoT);
  // 2) QKV projection -> Q(scaled)/K [B,H,T,D], V^T [B,H,D,T]
  gemm128<0><<<dim3(24, 64), 256, 0, stream>>>(
      Xb, WqT, bqkv, Qb, Kb, Vt, nullptr, 3072, 1024);
  // 3) causal flash attention -> Ob [B,T,C] bf16 (overwrites Xb)
  attn_fa<<<dim3(64, 16), 256, 0, stream>>>(Qb, Kb, Vt, Xb);
  // 4) out projection -> fp32 d_out
  gemm128<1><<<dim3(8, 64), 256, 0, stream>>>(
      Xb, WoT, bout, nullptr, nullptr, nullptr, (float*)d_out, 1024, 1024);
}

// Round 8
// 244.814 us; speedup vs baseline: 1.0493x; 1.0493x over previous
//
#include <hip/hip_runtime.h>
#include <math.h>

typedef unsigned short u16;
using bf16x8   = __attribute__((ext_vector_type(8))) __bf16;
using floatx4  = __attribute__((ext_vector_type(4))) float;
using ushortx8 = __attribute__((ext_vector_type(8))) unsigned short;
using ushortx4 = __attribute__((ext_vector_type(4))) unsigned short;
using uintx4   = __attribute__((ext_vector_type(4))) unsigned int;
using uintx2   = __attribute__((ext_vector_type(2))) unsigned int;

// round-half-up fp32->bf16
static __device__ __forceinline__ u16 f2bf(float f) {
  return (u16)((__float_as_uint(f) + 0x8000u) >> 16);
}
// pack two fp32 -> two bf16 in one u32
static __device__ __forceinline__ unsigned int pk2bf(float lo, float hi) {
#if __has_builtin(__builtin_amdgcn_cvt_pk_bf16_f32)
  typedef __attribute__((ext_vector_type(2))) __bf16 bf16x2_t;
  bf16x2_t r = __builtin_amdgcn_cvt_pk_bf16_f32(lo, hi);
  return *(unsigned int*)&r;
#else
  return __builtin_amdgcn_perm(__float_as_uint(hi) + 0x8000u,
                               __float_as_uint(lo) + 0x8000u, 0x07060302u);
#endif
}
// raw v_exp_f32 (2^x) — inputs bounded, skip denormal legalization
static __device__ __forceinline__ float fast_exp2(float x) {
#if __has_builtin(__builtin_amdgcn_exp2f)
  return __builtin_amdgcn_exp2f(x);
#else
  return exp2f(x);
#endif
}
static __device__ __forceinline__ float fast_rcp(float x) {
#if __has_builtin(__builtin_amdgcn_rcpf)
  return __builtin_amdgcn_rcpf(x);
#else
  return 1.0f / x;
#endif
}
// async global->LDS, 16B per lane; LDS dest = base + lane*16
static __device__ __forceinline__ void gload_lds16(const void* g, void* l) {
  __builtin_amdgcn_global_load_lds(
      (const __attribute__((address_space(1))) unsigned int*)g,
      (__attribute__((address_space(3))) unsigned int*)l, 16, 0, 0);
}

// ---------------------------------------------------------------------------
// Fused prep: x fp32->bf16  +  W_qkv transpose  +  W_out transpose.
// ---------------------------------------------------------------------------
static __device__ __forceinline__ void transW_tile(
    const float* __restrict__ W, u16* __restrict__ WT, int K, int N,
    int bx, int by, float (*tile)[68], int t) {
  const int kb = by * 64, nb = bx * 64;
  {
    const int kl = t >> 2, nc = (t & 3) * 16;
    const float* src = W + (size_t)(kb + kl) * N + nb + nc;
    #pragma unroll
    for (int c = 0; c < 4; c++)
      *(floatx4*)&tile[kl][nc + c * 4] = *(const floatx4*)(src + c * 4);
  }
  __syncthreads();
  {
    const int nl = t >> 2, kc = (t & 3) * 16;
    uintx4 u0, u1;
    #pragma unroll
    for (int j = 0; j < 4; j++)
      u0[j] = pk2bf(tile[kc + 2 * j][nl], tile[kc + 2 * j + 1][nl]);
    #pragma unroll
    for (int j = 0; j < 4; j++)
      u1[j] = pk2bf(tile[kc + 8 + 2 * j][nl], tile[kc + 9 + 2 * j][nl]);
    u16* dst = WT + (size_t)(nb + nl) * K + kb + kc;
    *(uintx4*)dst = u0;
    *(uintx4*)(dst + 8) = u1;
  }
}

__global__ __launch_bounds__(256) void prep(
    const float* __restrict__ x, const float* __restrict__ Wqkv,
    const float* __restrict__ Wout, u16* __restrict__ Xb,
    u16* __restrict__ WqT, u16* __restrict__ WoT) {
  __shared__ float tile[64][68];
  const int blk = blockIdx.x;
  const int t = threadIdx.x;
  if (blk < 4096) {
    const int i = (blk * 256 + t) * 8;
    floatx4 f0 = *(const floatx4*)(x + i);
    floatx4 f1 = *(const floatx4*)(x + i + 4);
    uintx4 u;
    u[0] = pk2bf(f0[0], f0[1]); u[1] = pk2bf(f0[2], f0[3]);
    u[2] = pk2bf(f1[0], f1[1]); u[3] = pk2bf(f1[2], f1[3]);
    *(uintx4*)(Xb + i) = u;
  } else if (blk < 4096 + 768) {
    const int b2 = blk - 4096;                 // 48 x 16
    transW_tile(Wqkv, WqT, 1024, 3072, b2 % 48, b2 / 48, tile, t);
  } else {
    const int b3 = blk - 4096 - 768;           // 16 x 16
    transW_tile(Wout, WoT, 1024, 1024, b3 % 16, b3 / 16, tile, t);
  }
}

// ---------------------------------------------------------------------------
// GEMM  C[M,N] = A[M,K](bf16) @ B^T[N,K](bf16)^T + bias.  128x128, BK=64.
// Both operands staged via global_load_lds, XOR-swizzled 8-elem k-chunks.
// OUT==0 (round-5 proven): unswapped loop; scatter Q(scaled)/K [B,H,T,D]
//        scalar + V^T [B,H,D,T] packed.
// OUT==1: operand-swapped loop (acc reg dim = n) -> packed floatx4 + bias.
// ---------------------------------------------------------------------------
template <int OUT>
__global__ __launch_bounds__(256) void gemm128(
    const u16* __restrict__ A, const u16* __restrict__ Bt,
    const float* __restrict__ bias,
    u16* __restrict__ Qb, u16* __restrict__ Kb, u16* __restrict__ Vt,
    float* __restrict__ Out, int N, int K)
{
  __shared__ u16 As[128 * 64];
  __shared__ u16 Bs[128 * 64];

  const int tid  = threadIdx.x;
  const int wave = tid >> 6, lane = tid & 63;
  const int quad = lane >> 4, l15 = lane & 15;
  const int lrow = lane >> 3;                 // 0..7
  const int scol = ((lane & 7) ^ lrow) * 8;   // swizzled k-offset (elements)

  const int rowBase = blockIdx.y * 128;
  const int colBase = blockIdx.x * 128;
  const int wRow = (wave >> 1) * 64;
  const int wCol = (wave & 1) * 64;

  floatx4 acc[4][4];
  #pragma unroll
  for (int i = 0; i < 4; i++)
    #pragma unroll
    for (int j = 0; j < 4; j++)
      acc[i][j] = floatx4{0.f, 0.f, 0.f, 0.f};

  const u16* Ap = A  + (size_t)(rowBase + (wave * 4) * 8 + lrow) * K + scol;
  const u16* Bp = Bt + (size_t)(colBase + (wave * 4) * 8 + lrow) * K + scol;

  for (int k0 = 0; k0 < K; k0 += 64) {
    __syncthreads();
    #pragma unroll
    for (int i = 0; i < 4; i++) {
      const int c = wave * 4 + i;
      gload_lds16(Ap + (size_t)(i * 8) * K + k0, &As[c * 512]);
      gload_lds16(Bp + (size_t)(i * 8) * K + k0, &Bs[c * 512]);
    }
    __syncthreads();

    #pragma unroll
    for (int ks = 0; ks < 2; ks++) {
      const int sw = (((ks << 2) | quad) ^ (l15 & 7)) << 3;
      bf16x8 a[4], b[4];
      #pragma unroll
      for (int mt = 0; mt < 4; mt++)
        a[mt] = *(const bf16x8*)&As[(wRow + mt * 16 + l15) * 64 + sw];
      #pragma unroll
      for (int nt = 0; nt < 4; nt++)
        b[nt] = *(const bf16x8*)&Bs[(wCol + nt * 16 + l15) * 64 + sw];
      if constexpr (OUT == 0) {
        #pragma unroll
        for (int mt = 0; mt < 4; mt++)
          #pragma unroll
          for (int nt = 0; nt < 4; nt++)
            acc[mt][nt] = __builtin_amdgcn_mfma_f32_16x16x32_bf16(a[mt], b[nt], acc[mt][nt], 0, 0, 0);
      } else {
        #pragma unroll
        for (int nt = 0; nt < 4; nt++)
          #pragma unroll
          for (int mt = 0; mt < 4; mt++)
            acc[nt][mt] = __builtin_amdgcn_mfma_f32_16x16x32_bf16(b[nt], a[mt], acc[nt][mt], 0, 0, 0);
      }
    }
  }

  if constexpr (OUT == 0) {
    const int which = colBase >> 10;            // block-uniform: 0=Q 1=K 2=V
    const int cb = colBase & 1023;
    const float qscale = 0.18033688011112042f;  // 0.125 * log2(e) -> softmax uses exp2
    #pragma unroll
    for (int mt = 0; mt < 4; mt++) {
      const int gm0 = rowBase + wRow + mt * 16 + quad * 4;
      const int bb = gm0 >> 11, t0 = gm0 & 2047;
      #pragma unroll
      for (int nt = 0; nt < 4; nt++) {
        const int gn = colBase + wCol + nt * 16 + l15;
        const int gl = cb + wCol + nt * 16 + l15;
        const float bv = bias[gn];
        const int h = gl >> 6, d = gl & 63;
        const int bh = bb * 16 + h;
        if (which == 2) {
          ushortx4 pk;
          #pragma unroll
          for (int r = 0; r < 4; r++) pk[r] = f2bf(acc[mt][nt][r] + bv);
          *(ushortx4*)&Vt[((size_t)bh * 64 + d) * 2048 + t0] = pk;   // V^T [B,H,D,T]
        } else if (which == 0) {
          #pragma unroll
          for (int r = 0; r < 4; r++)
            Qb[((size_t)bh * 2048 + t0 + r) * 64 + d] = f2bf((acc[mt][nt][r] + bv) * qscale);
        } else {
          #pragma unroll
          for (int r = 0; r < 4; r++)
            Kb[((size_t)bh * 2048 + t0 + r) * 64 + d] = f2bf(acc[mt][nt][r] + bv);
        }
      }
    }
  } else {
    // swapped epilogue: packed dwordx4 fp32 stores
    #pragma unroll
    for (int nt = 0; nt < 4; nt++) {
      const int gn0 = colBase + wCol + nt * 16 + quad * 4;
      const floatx4 bv = *(const floatx4*)&bias[gn0];
      #pragma unroll
      for (int mt = 0; mt < 4; mt++) {
        const int gm = rowBase + wRow + mt * 16 + l15;
        floatx4 v = acc[nt][mt] + bv;
        *(floatx4*)&Out[(size_t)gm * N + gn0] = v;
      }
    }
  }
}

// ---------------------------------------------------------------------------
// Flash attention, causal, softmax-lite, transposed score path (round-5 body),
// WORK-BALANCED: each block processes q-tile pair (y, 15-y) -> uniform 34
// k-tiles/block, grid 64x8, no tail.
// LDS: Qs 16K (reused as Pt) + Ks 8K + Vs 8K = 32 KB.
// ---------------------------------------------------------------------------
__global__ __launch_bounds__(256) void attn_fa(
    const u16* __restrict__ Qb, const u16* __restrict__ Kb,
    const u16* __restrict__ Vt, u16* __restrict__ Ob)
{
  __shared__ u16 Qs[128 * 64];             // Q staging; reused as Pt after aq reads
  __shared__ u16 Ks[64 * 64], Vs[64 * 64]; // swizzled

  const int tid  = threadIdx.x;
  const int wave = tid >> 6, lane = tid & 63;
  const int quad = lane >> 4, l15 = lane & 15;
  const int lrow = lane >> 3;
  const int scol = ((lane & 7) ^ lrow) * 8;

  u16* Pt = &Qs[wave * 16 * 72];           // per-wave P^T tile [q=16][key=64], pad 72

  const int bh = blockIdx.x;               // b*16 + h
  const int y  = blockIdx.y;               // 0..7 -> q-tile pair (y, 15-y)

  const u16* Qp = Qb + (size_t)bh * 2048 * 64;
  const u16* Kp = Kb + (size_t)bh * 2048 * 64;
  const u16* Vp = Vt + (size_t)bh * 64 * 2048;

  const int swA0 = (quad ^ (l15 & 7)) * 8;        // k-chunk 0..3 swizzle
  const int swA1 = ((4 + quad) ^ (l15 & 7)) * 8;  // k-chunk 4..7 swizzle
  const int bb = bh >> 4, h = bh & 15;

  for (int ph = 0; ph < 2; ph++) {
    const int qt = ph ? (15 - y) : y;
    const int qbase = qt * 128;

    __syncthreads();   // prior phase's LDS reads (Pt/Ks/Vs) complete
    #pragma unroll
    for (int i = 0; i < 4; i++) {
      const int c = wave * 4 + i;
      gload_lds16(Qp + (size_t)(qbase + c * 8 + lrow) * 64 + scol, &Qs[c * 512]);
    }
    __syncthreads();

    bf16x8 aq[2][2];
    #pragma unroll
    for (int mt = 0; mt < 2; mt++) {
      const int row = wave * 32 + mt * 16 + l15;
      aq[mt][0] = *(const bf16x8*)&Qs[row * 64 + swA0];
      aq[mt][1] = *(const bf16x8*)&Qs[row * 64 + swA1];
    }
    // all aq ds_reads complete before the k-loop's first barrier -> Pt overlay safe

    floatx4 o[2][4];
    #pragma unroll
    for (int mt = 0; mt < 2; mt++)
      #pragma unroll
      for (int dt = 0; dt < 4; dt++) o[mt][dt] = floatx4{0.f, 0.f, 0.f, 0.f};
    float lsum[2] = {0.f, 0.f};

    const int rowmax = qbase + wave * 32 + 31;   // wave's highest q index
    const int nk = 2 * qt + 2;
    for (int kt = 0; kt < nk; kt++) {
      const int kbase = kt * 64;
      __syncthreads();   // previous tile's LDS reads complete
      #pragma unroll
      for (int i = 0; i < 2; i++) {
        const int c = wave * 2 + i;
        gload_lds16(Kp + (size_t)(kbase + c * 8 + lrow) * 64 + scol, &Ks[c * 512]);
        gload_lds16(Vp + (size_t)(c * 8 + lrow) * 2048 + kbase + scol, &Vs[c * 512]);
      }
      __syncthreads();   // staging visible

      if (kbase > rowmax) continue;   // fully masked for this wave

      // hoisted mt-invariant fragments: K (B-op of S^T) and V (A-op of O^T)
      bf16x8 kf[4][2], vf[4][2];
      #pragma unroll
      for (int ct = 0; ct < 4; ct++) {
        const int row = ct * 16 + l15;
        kf[ct][0] = *(const bf16x8*)&Ks[row * 64 + swA0];
        kf[ct][1] = *(const bf16x8*)&Ks[row * 64 + swA1];
        vf[ct][0] = *(const bf16x8*)&Vs[row * 64 + swA0];
        vf[ct][1] = *(const bf16x8*)&Vs[row * 64 + swA1];
      }

      #pragma unroll
      for (int mt = 0; mt < 2; mt++) {
        const int rowmin = qbase + wave * 32 + mt * 16;
        if (kbase > rowmin + 15) continue;          // subtile fully masked
        const bool needmask = (kbase + 63 > rowmin);

        // S^T = K Q^T : st[ct][r] = S[q=rowmin+l15][key=kbase+ct*16+quad*4+r]
        floatx4 st[4];
        #pragma unroll
        for (int ct = 0; ct < 4; ct++) {
          floatx4 z = floatx4{0.f, 0.f, 0.f, 0.f};
          z      = __builtin_amdgcn_mfma_f32_16x16x32_bf16(kf[ct][0], aq[mt][0], z, 0, 0, 0);
          st[ct] = __builtin_amdgcn_mfma_f32_16x16x32_bf16(kf[ct][1], aq[mt][1], z, 0, 0, 0);
        }

        // p = exp2(s) (raw v_exp_f32), mask, pack, partial row-sum (q = l15)
        const int qg = rowmin + l15;
        float ls = 0.f;
        #pragma unroll
        for (int ct = 0; ct < 4; ct++) {
          float p0 = fast_exp2(st[ct][0]), p1 = fast_exp2(st[ct][1]);
          float p2 = fast_exp2(st[ct][2]), p3 = fast_exp2(st[ct][3]);
          if (needmask) {
            const int k0i = kbase + ct * 16 + quad * 4;
            if (k0i + 0 > qg) p0 = 0.f;
            if (k0i + 1 > qg) p1 = 0.f;
            if (k0i + 2 > qg) p2 = 0.f;
            if (k0i + 3 > qg) p3 = 0.f;
          }
          ls += (p0 + p1) + (p2 + p3);
          uintx2 w;
          w[0] = pk2bf(p0, p1);
          w[1] = pk2bf(p2, p3);
          *(uintx2*)&Pt[l15 * 72 + ct * 16 + quad * 4] = w;   // ds_write_b64
        }
        lsum[mt] += ls;

        // O^T += V^T P^T  (Pt re-read as B-operand; in-order DS per wave)
        const bf16x8 pb0 = *(const bf16x8*)&Pt[l15 * 72 + quad * 8];
        const bf16x8 pb1 = *(const bf16x8*)&Pt[l15 * 72 + 32 + quad * 8];
        #pragma unroll
        for (int dt = 0; dt < 4; dt++) {
          o[mt][dt] = __builtin_amdgcn_mfma_f32_16x16x32_bf16(vf[dt][0], pb0, o[mt][dt], 0, 0, 0);
          o[mt][dt] = __builtin_amdgcn_mfma_f32_16x16x32_bf16(vf[dt][1], pb1, o[mt][dt], 0, 0, 0);
        }
      }
    }

    // epilogue: reduce row-sums across quads, normalize, packed 8B stores
    #pragma unroll
    for (int mt = 0; mt < 2; mt++) {
      float l = lsum[mt];
      l += __shfl_xor(l, 16);
      l += __shfl_xor(l, 32);
      const float linv = fast_rcp(l);
      const int t = qbase + wave * 32 + mt * 16 + l15;
      u16* dst = Ob + ((size_t)(bb * 2048 + t)) * 1024 + h * 64 + quad * 4;
      #pragma unroll
      for (int dt = 0; dt < 4; dt++) {
        uintx2 w;
        w[0] = pk2bf(o[mt][dt][0] * linv, o[mt][dt][1] * linv);
        w[1] = pk2bf(o[mt][dt][2] * linv, o[mt][dt][3] * linv);
        *(uintx2*)(dst + dt * 16) = w;
      }
    }
  }
}

// ---------------------------------------------------------------------------
extern "C" void kernel_launch(void* const* d_in, const int* in_sizes, int n_in,
                              void* d_out, int out_size, void* d_ws, size_t ws_size,
                              hipStream_t stream) {
  const float* x    = (const float*)d_in[0];
  const float* Wqkv = (const float*)d_in[1];
  const float* bqkv = (const float*)d_in[2];
  const float* Wout = (const float*)d_in[3];
  const float* bout = (const float*)d_in[4];

  // workspace (u16 elems), 75.5 MB total:
  //  Xb (x bf16, reused as Ob) | WqT | WoT | Qb | Kb | Vt
  const size_t NB = (size_t)8192 * 1024;
  u16* Xb  = (u16*)d_ws;               // also Ob
  u16* WqT = Xb + NB;
  u16* WoT = WqT + (size_t)3072 * 1024;
  u16* Qb  = WoT + (size_t)1024 * 1024;
  u16* Kb  = Qb + NB;
  u16* Vt  = Kb + NB;

  // 1) fused prep: x->bf16, Wqkv^T, Wout^T
  prep<<<5120, 256, 0, stream>>>(x, Wqkv, Wout, Xb, WqT, WoT);
  // 2) QKV projection -> Q(scaled)/K [B,H,T,D], V^T [B,H,D,T]
  gemm128<0><<<dim3(24, 64), 256, 0, stream>>>(
      Xb, WqT, bqkv, Qb, Kb, Vt, nullptr, 3072, 1024);
  // 3) causal flash attention, work-balanced q-tile pairs -> Ob (overwrites Xb)
  attn_fa<<<dim3(64, 8), 256, 0, stream>>>(Qb, Kb, Vt, Xb);
  // 4) out projection -> fp32 d_out
  gemm128<1><<<dim3(8, 64), 256, 0, stream>>>(
      Xb, WoT, bout, nullptr, nullptr, nullptr, (float*)d_out, 1024, 1024);
}